// Round 8
// baseline (1142.090 us; speedup 1.0000x reference)
//
#include <hip/hip_runtime.h>
#include <hip/hip_cooperative_groups.h>

namespace cg = cooperative_groups;

#define N_NODES 50000
#define N_EDGES 100000
#define DD 32
#define STEPS 5
#define ETYPES 8
#define CAP_T 13312              // per-type slot capacity (mult of 64; mean 12500, sigma~105)
#define CAP (ETYPES * CAP_T)     // 106496 sorted slots
#define NCHUNK (CAP / 64)        // 1664 edge chunks (64 slots each, type-uniform)
#define TRASH N_EDGES            // trash row index in fea arrays (extra row allocated)
#define SCAN_B 49                // 49 blocks * 1024 = 50176 >= N_NODES

#define NPT 4            // nodes per thread (gru)
#define NPB 128          // nodes per block (gru)
#define NGB ((N_NODES + NPB - 1) / NPB)   // 391 gru work items
#define SMEM_F4 (NPB * 17)       // 2176 float4 = 34816 B shared (cat / edge-W union)

// ------------------------- setup kernels (proven R3-R7) ---------------------

__global__ void init_kernel(const int* __restrict__ token,
                            const float* __restrict__ emb,
                            float* __restrict__ prop,
                            int* __restrict__ cnt,      // 2N+8: cnt_in | cnt_out | tcnt
                            int* __restrict__ se,
                            int* __restrict__ spi,
                            int* __restrict__ spo) {
    int idx = blockIdx.x * 256 + threadIdx.x;   // over N*D = 1.6M, exact grid
    int n = idx >> 5, j = idx & 31;
    prop[idx] = emb[token[n] * DD + j];
    if (idx < 2 * N_NODES + ETYPES) cnt[idx] = 0;
    if (idx < CAP) { se[idx] = 0; spi[idx] = TRASH; spo[idx] = TRASH; }
}

__global__ void hist_kernel(const int* __restrict__ etype,
                            const int* __restrict__ src,
                            const int* __restrict__ dst,
                            int* __restrict__ cnt_in, int* __restrict__ cnt_out,
                            int* __restrict__ tcnt,
                            int* __restrict__ rank_in, int* __restrict__ rank_out,
                            int* __restrict__ qe) {
    __shared__ int lh[ETYPES], lbase[ETYPES];
    int tid = threadIdx.x;
    int e = blockIdx.x * 256 + tid;
    if (tid < ETYPES) lh[tid] = 0;
    __syncthreads();
    int t = 0, lr = 0;
    bool v = e < N_EDGES;
    if (v) {
        t = etype[e];
        lr = atomicAdd(&lh[t], 1);
        rank_in[e]  = atomicAdd(&cnt_in[dst[e]], 1);
        rank_out[e] = atomicAdd(&cnt_out[src[e]], 1);
    }
    __syncthreads();
    if (tid < ETYPES) lbase[tid] = atomicAdd(&tcnt[tid], lh[tid]);
    __syncthreads();
    if (v) qe[e] = t * CAP_T + lbase[t] + lr;
}

__global__ __launch_bounds__(1024) void
scan1(const int* __restrict__ cnt_in, const int* __restrict__ cnt_out,
      int* __restrict__ off_in, int* __restrict__ off_out,
      int* __restrict__ bsum) {
    __shared__ int s[1024];
    int b = blockIdx.x;
    int ab = (b < SCAN_B) ? b : b - SCAN_B;
    const int* a = (b < SCAN_B) ? cnt_in : cnt_out;
    int* o = (b < SCAN_B) ? off_in : off_out;
    int i = ab * 1024 + threadIdx.x;
    int x = (i < N_NODES) ? a[i] : 0;
    s[threadIdx.x] = x;
    __syncthreads();
    for (int ofs = 1; ofs < 1024; ofs <<= 1) {
        int u = (threadIdx.x >= ofs) ? s[threadIdx.x - ofs] : 0;
        __syncthreads();
        s[threadIdx.x] += u;
        __syncthreads();
    }
    if (i < N_NODES) o[i] = s[threadIdx.x] - x;   // local exclusive
    if (threadIdx.x == 1023) bsum[b] = s[1023];
}

__global__ void scan2(const int* __restrict__ bsum, int* __restrict__ ebase,
                      int* __restrict__ off_in, int* __restrict__ off_out) {
    __shared__ int s[128];
    int t = threadIdx.x;
    int x = (t < 2 * SCAN_B) ? bsum[t] : 0;
    s[t] = x;
    __syncthreads();
    for (int ofs = 1; ofs < 128; ofs <<= 1) {
        int u = (t >= ofs) ? s[t - ofs] : 0;
        __syncthreads();
        s[t] += u;
        __syncthreads();
    }
    if (t < SCAN_B) ebase[t] = s[t] - x;
    else if (t < 2 * SCAN_B) ebase[t] = s[t] - x - N_EDGES;
    if (t == 0) { off_in[N_NODES] = N_EDGES; off_out[N_NODES] = N_EDGES; }
}

__global__ __launch_bounds__(1024) void
scan3(int* __restrict__ off_in, int* __restrict__ off_out,
      const int* __restrict__ ebase) {
    int b = blockIdx.x;
    int ab = (b < SCAN_B) ? b : b - SCAN_B;
    int* o = (b < SCAN_B) ? off_in : off_out;
    int i = ab * 1024 + threadIdx.x;
    if (i < N_NODES) o[i] += ebase[b];
}

__global__ void place_kernel(const int* __restrict__ src,
                             const int* __restrict__ dst,
                             const int* __restrict__ in_off,
                             const int* __restrict__ out_off,
                             const int* __restrict__ rank_in,
                             const int* __restrict__ rank_out,
                             const int* __restrict__ qe,
                             int* __restrict__ se, int* __restrict__ spi,
                             int* __restrict__ spo) {
    int e = blockIdx.x * 256 + threadIdx.x;
    if (e < N_EDGES) {
        int q = qe[e];
        int pi = in_off[dst[e]]  + rank_in[e];
        int po = out_off[src[e]] + rank_out[e];
        if (q < CAP) {                          // guard: never OOB even on 8-sigma
            se[q]  = src[e];
            spi[q] = pi;
            spo[q] = po;
        }
    }
}

// ------------------------- shared phase bodies ------------------------------

// Edge chunk c: 64 type-uniform slots. W for the chunk's type staged to LDS
// (8 KB) so per-thread VGPR stays low (fused-kernel occupancy contract).
// Same slot enumeration / math as the R7-passing edge kernel.
__device__ __forceinline__ void edge_body(
    int c, const int* __restrict__ se, const int* __restrict__ spi,
    const int* __restrict__ spo, const float* __restrict__ W_edge,
    const float* __restrict__ prop,
    float* __restrict__ fea_in, float* __restrict__ fea_out,
    float4* wsm /* >= 512 float4 */) {
    const int tid = threadIdx.x;
    __syncthreads();                               // prior smem users done
    int type = (c * 64) / CAP_T;                   // chunk-uniform (CAP_T%64==0)
    const float4* Wt4 = (const float4*)(W_edge + (size_t)type * (DD * DD * 2));
    wsm[tid]       = Wt4[tid];                     // 512 float4 = 8 KB
    wsm[tid + 256] = Wt4[tid + 256];
    __syncthreads();
    const float2* w2 = (const float2*)wsm;         // [i*32+j] = (fwd,rev)
    int lane = tid & 63;
    int j = lane & 31;
    int slot0 = c * 64 + (tid >> 6) * 16 + ((lane >> 5) << 3);
    int s[8], pi[8], po[8];
    float h[8];
#pragma unroll
    for (int k = 0; k < 8; ++k) {
        s[k] = se[slot0 + k]; pi[k] = spi[slot0 + k]; po[k] = spo[slot0 + k];
    }
#pragma unroll
    for (int k = 0; k < 8; ++k) h[k] = prop[(size_t)s[k] * DD + j];
    float aF[8] = {0.f,0.f,0.f,0.f,0.f,0.f,0.f,0.f};
    float aR[8] = {0.f,0.f,0.f,0.f,0.f,0.f,0.f,0.f};
#pragma unroll
    for (int i = 0; i < DD; ++i) {
        float2 wv = w2[i * DD + j];                // LDS broadcast row
#pragma unroll
        for (int k = 0; k < 8; ++k) {
            float hi = __shfl(h[k], i, 32);        // broadcast within half-wave
            aF[k] = fmaf(hi, wv.x, aF[k]);
            aR[k] = fmaf(hi, wv.y, aR[k]);
        }
    }
#pragma unroll
    for (int k = 0; k < 8; ++k) {
        fea_in [(size_t)pi[k] * DD + j] = aF[k];   // plain 128B-row stores
        fea_out[(size_t)po[k] * DD + j] = aR[k];
    }
}

__device__ __forceinline__ void fma4(float (&acc)[4], float c, const float4& w) {
    acc[0] = fmaf(c, w.x, acc[0]);
    acc[1] = fmaf(c, w.y, acc[1]);
    acc[2] = fmaf(c, w.z, acc[2]);
    acc[3] = fmaf(c, w.w, acc[3]);
}
__device__ __forceinline__ float sigm(float x) {
    return 1.f / (1.f + __expf(-x));
}
__device__ __forceinline__ float fast_tanh(float x) {
    x = fminf(fmaxf(x, -15.f), 15.f);
    float e = __expf(2.f * x);
    return (e - 1.f) / (e + 1.f);
}

// GRU block nb: 128 nodes, NPT=4 (R7-verified structure: per-node CSR gather
// into cat[in|out], prop in registers, rows 64-95 via 8-lane shfl broadcast;
// weights from global = L1-hot broadcast loads).
__device__ __forceinline__ void gru_body(
    int nb,
    const float* __restrict__ W_r, const float* __restrict__ b_r,
    const float* __restrict__ W_z, const float* __restrict__ b_z,
    const float* __restrict__ W_t, const float* __restrict__ b_t,
    const float* __restrict__ fea_in, const float* __restrict__ fea_out,
    const int* __restrict__ in_off, const int* __restrict__ out_off,
    float* __restrict__ prop, float* __restrict__ out2,
    float* cat /* >= NPB*68 floats smem */) {
    float4* cat4 = (float4*)cat;                  // row stride 17 float4
    const int tid = threadIdx.x;
    const int n0 = nb * NPB;
    const int jq = tid & 7;
    const int ng = tid >> 3;
    __syncthreads();                              // prior smem users done

    // prop -> registers (thread mapping == matvec mapping)
    float p_[NPT][4];
    {
        const float4* p4 = (const float4*)(prop + (size_t)n0 * DD);
        const float4 zz = {0.f, 0.f, 0.f, 0.f};
#pragma unroll
        for (int k = 0; k < NPT; ++k) {
            int f = k * 256 + tid;                // node = f>>3, quad jq
            float4 p = (n0 + (f >> 3) < N_NODES) ? p4[f] : zz;
            p_[k][0] = p.x; p_[k][1] = p.y; p_[k][2] = p.z; p_[k][3] = p.w;
        }
    }
    // per-node CSR gather of in/out segment sums (exclusive writes)
    {
        const float4* fi4 = (const float4*)fea_in;    // row = 8 float4
        const float4* fo4 = (const float4*)fea_out;
        const float4 zz = {0.f, 0.f, 0.f, 0.f};
#pragma unroll
        for (int q = 0; q < 4; ++q) {
            int f = q * 256 + tid;                    // (node,c4) pair
            int node = f >> 3;
            int c4 = f & 7;
            int gn = n0 + node;
            float4 va = zz, vb = zz;
            if (gn < N_NODES) {
                int i0 = in_off[gn], i1 = in_off[gn + 1];
                for (int r = i0; r < i1; ++r) {
                    float4 x = fi4[(size_t)r * 8 + c4];
                    va.x += x.x; va.y += x.y; va.z += x.z; va.w += x.w;
                }
                int o0 = out_off[gn], o1 = out_off[gn + 1];
                for (int r = o0; r < o1; ++r) {
                    float4 x = fo4[(size_t)r * 8 + c4];
                    vb.x += x.x; vb.y += x.y; vb.z += x.z; vb.w += x.w;
                }
            }
            cat4[node * 17 + c4]     = va;
            cat4[node * 17 + 8 + c4] = vb;
        }
    }
    __syncthreads();

    // phase A: r,z
    float r_[NPT][4], z_[NPT][4];
    {
        float4 br = ((const float4*)b_r)[jq];
        float4 bz = ((const float4*)b_z)[jq];
#pragma unroll
        for (int k = 0; k < NPT; ++k) {
            r_[k][0] = br.x; r_[k][1] = br.y; r_[k][2] = br.z; r_[k][3] = br.w;
            z_[k][0] = bz.x; z_[k][1] = bz.y; z_[k][2] = bz.z; z_[k][3] = bz.w;
        }
    }
#pragma unroll 1
    for (int g = 0; g < 16; ++g) {                // rows 0..63 from cat LDS
        int m0 = g * 4;
        float4 wr[4], wz[4];
#pragma unroll
        for (int i = 0; i < 4; ++i) {
            wr[i] = ((const float4*)(W_r + (m0 + i) * DD))[jq];
            wz[i] = ((const float4*)(W_z + (m0 + i) * DD))[jq];
        }
#pragma unroll
        for (int k = 0; k < NPT; ++k) {
            float4 c = cat4[(ng + 32 * k) * 17 + g];
            fma4(r_[k], c.x, wr[0]); fma4(r_[k], c.y, wr[1]);
            fma4(r_[k], c.z, wr[2]); fma4(r_[k], c.w, wr[3]);
            fma4(z_[k], c.x, wz[0]); fma4(z_[k], c.y, wz[1]);
            fma4(z_[k], c.z, wz[2]); fma4(z_[k], c.w, wz[3]);
        }
    }
#pragma unroll 1
    for (int i2 = 0; i2 < 8; ++i2) {              // rows 64..95: prop via shfl
        float4 wr[4], wz[4];
#pragma unroll
        for (int c = 0; c < 4; ++c) {
            wr[c] = ((const float4*)(W_r + (64 + i2 * 4 + c) * DD))[jq];
            wz[c] = ((const float4*)(W_z + (64 + i2 * 4 + c) * DD))[jq];
        }
#pragma unroll
        for (int k = 0; k < NPT; ++k) {
            float pc0 = __shfl(p_[k][0], i2, 8);
            float pc1 = __shfl(p_[k][1], i2, 8);
            float pc2 = __shfl(p_[k][2], i2, 8);
            float pc3 = __shfl(p_[k][3], i2, 8);
            fma4(r_[k], pc0, wr[0]); fma4(r_[k], pc1, wr[1]);
            fma4(r_[k], pc2, wr[2]); fma4(r_[k], pc3, wr[3]);
            fma4(z_[k], pc0, wz[0]); fma4(z_[k], pc1, wz[1]);
            fma4(z_[k], pc2, wz[2]); fma4(z_[k], pc3, wz[3]);
        }
    }
#pragma unroll
    for (int k = 0; k < NPT; ++k)
#pragma unroll
        for (int j = 0; j < 4; ++j) {
            r_[k][j] = sigm(r_[k][j]) * p_[k][j];     // r := r*p
            z_[k][j] = sigm(z_[k][j]);
        }

    // phase B: t
    float t_[NPT][4];
    {
        float4 bt = ((const float4*)b_t)[jq];
#pragma unroll
        for (int k = 0; k < NPT; ++k) {
            t_[k][0] = bt.x; t_[k][1] = bt.y; t_[k][2] = bt.z; t_[k][3] = bt.w;
        }
    }
#pragma unroll 1
    for (int g = 0; g < 16; ++g) {
        int m0 = g * 4;
        float4 wt[4];
#pragma unroll
        for (int i = 0; i < 4; ++i)
            wt[i] = ((const float4*)(W_t + (m0 + i) * DD))[jq];
#pragma unroll
        for (int k = 0; k < NPT; ++k) {
            float4 c = cat4[(ng + 32 * k) * 17 + g];
            fma4(t_[k], c.x, wt[0]); fma4(t_[k], c.y, wt[1]);
            fma4(t_[k], c.z, wt[2]); fma4(t_[k], c.w, wt[3]);
        }
    }
#pragma unroll 1
    for (int i2 = 0; i2 < 8; ++i2) {
        float4 wt[4];
#pragma unroll
        for (int c = 0; c < 4; ++c)
            wt[c] = ((const float4*)(W_t + (64 + i2 * 4 + c) * DD))[jq];
#pragma unroll
        for (int k = 0; k < NPT; ++k) {
            float rc0 = __shfl(r_[k][0], i2, 8);
            float rc1 = __shfl(r_[k][1], i2, 8);
            float rc2 = __shfl(r_[k][2], i2, 8);
            float rc3 = __shfl(r_[k][3], i2, 8);
            fma4(t_[k], rc0, wt[0]); fma4(t_[k], rc1, wt[1]);
            fma4(t_[k], rc2, wt[2]); fma4(t_[k], rc3, wt[3]);
        }
    }

    // update: prop = p + z*(tanh(t) - p); final step also writes out2
#pragma unroll
    for (int k = 0; k < NPT; ++k) {
        int node = n0 + ng + 32 * k;
        if (node < N_NODES) {
            float4 o;
            o.x = fmaf(z_[k][0], fast_tanh(t_[k][0]) - p_[k][0], p_[k][0]);
            o.y = fmaf(z_[k][1], fast_tanh(t_[k][1]) - p_[k][1], p_[k][1]);
            o.z = fmaf(z_[k][2], fast_tanh(t_[k][2]) - p_[k][2], p_[k][2]);
            o.w = fmaf(z_[k][3], fast_tanh(t_[k][3]) - p_[k][3], p_[k][3]);
            ((float4*)(prop + (size_t)node * DD))[jq] = o;
            if (out2) ((float4*)(out2 + (size_t)node * DD))[jq] = o;
        }
    }
}

// ------------------------- fused cooperative kernel -------------------------
// All 5 steps in one dispatch: edge phase (grid-stride over 1664 chunks) ->
// grid.sync -> gru phase (grid-stride over 391 node-blocks) -> grid.sync.
// __launch_bounds__(256,4) pins VGPR<=128 so LDS (34.8KB -> 4 blocks/CU) is
// the binding co-residency limit; grid is sized by the occupancy query.
__global__ __launch_bounds__(256, 4) void
fused_steps(const int* __restrict__ se, const int* __restrict__ spi,
            const int* __restrict__ spo, const float* __restrict__ W_edge,
            const float* __restrict__ W_r, const float* __restrict__ b_r,
            const float* __restrict__ W_z, const float* __restrict__ b_z,
            const float* __restrict__ W_t, const float* __restrict__ b_t,
            float* __restrict__ fea_in, float* __restrict__ fea_out,
            const int* __restrict__ in_off, const int* __restrict__ out_off,
            float* __restrict__ prop, float* __restrict__ out) {
    __shared__ float4 smem[SMEM_F4];              // 34816 B (cat / edge-W union)
    cg::grid_group grid = cg::this_grid();
    const int G = gridDim.x;
    for (int step = 0; step < STEPS; ++step) {
        for (int c = blockIdx.x; c < NCHUNK; c += G)
            edge_body(c, se, spi, spo, W_edge, prop, fea_in, fea_out, smem);
        grid.sync();                              // fea complete
        float* o2 = (step == STEPS - 1) ? out : nullptr;
        for (int nb = blockIdx.x; nb < NGB; nb += G)
            gru_body(nb, W_r, b_r, W_z, b_z, W_t, b_t, fea_in, fea_out,
                     in_off, out_off, prop, o2, (float*)smem);
        grid.sync();                              // prop complete
    }
}

// ------------------------- fallback per-step kernels ------------------------

__global__ __launch_bounds__(256) void
edge_kernel(const int* __restrict__ se, const int* __restrict__ spi,
            const int* __restrict__ spo, const float* __restrict__ W_edge,
            const float* __restrict__ prop,
            float* __restrict__ fea_in, float* __restrict__ fea_out) {
    __shared__ float4 wsm[512];
    edge_body(blockIdx.x, se, spi, spo, W_edge, prop, fea_in, fea_out, wsm);
}

__global__ __launch_bounds__(256) void
gru_kernel(const float* __restrict__ W_r, const float* __restrict__ b_r,
           const float* __restrict__ W_z, const float* __restrict__ b_z,
           const float* __restrict__ W_t, const float* __restrict__ b_t,
           const float* __restrict__ fea_in, const float* __restrict__ fea_out,
           const int* __restrict__ in_off, const int* __restrict__ out_off,
           float* __restrict__ prop, float* __restrict__ out2) {
    __shared__ float4 smem[SMEM_F4];
    gru_body(blockIdx.x, W_r, b_r, W_z, b_z, W_t, b_t, fea_in, fea_out,
             in_off, out_off, prop, out2, (float*)smem);
}

// ----------------------------------------------------------------------------

extern "C" void kernel_launch(void* const* d_in, const int* in_sizes, int n_in,
                              void* d_out, int out_size, void* d_ws, size_t ws_size,
                              hipStream_t stream) {
    const int*   token  = (const int*)d_in[0];
    const int*   etype  = (const int*)d_in[1];
    const int*   src    = (const int*)d_in[2];
    const int*   dst    = (const int*)d_in[3];
    const float* emb    = (const float*)d_in[4];
    const float* W_edge = (const float*)d_in[5];
    const float* W_r    = (const float*)d_in[6];
    const float* b_r    = (const float*)d_in[7];
    const float* W_z    = (const float*)d_in[8];
    const float* b_z    = (const float*)d_in[9];
    const float* W_t    = (const float*)d_in[10];
    const float* b_t    = (const float*)d_in[11];
    float* out = (float*)d_out;

    // Persistent workspace (~33 MB; ws_size = 256 MB per the poison fill):
    float* prop    = (float*)d_ws;                            // N*D
    float* fea_in  = prop    + (size_t)N_NODES * DD;          // (E+1)*D
    float* fea_out = fea_in  + (size_t)(N_EDGES + 1) * DD;    // (E+1)*D
    int* in_off   = (int*)(fea_out + (size_t)(N_EDGES + 1) * DD); // N+1
    int* out_off  = in_off + (N_NODES + 1);                   // N+1
    int* se       = out_off + (N_NODES + 1);                  // CAP
    int* spi      = se + CAP;                                 // CAP
    int* spo      = spi + CAP;                                // CAP

    // Setup temporaries OVERLAID on fea_in (dead before first edge write).
    int* cnt      = (int*)fea_in;                             // 2N+8
    int* cnt_in   = cnt;
    int* cnt_out  = cnt + N_NODES;
    int* tcnt     = cnt + 2 * N_NODES;
    int* rank_in  = cnt + 2 * N_NODES + ETYPES;               // E
    int* rank_out = rank_in + N_EDGES;                        // E
    int* qe       = rank_out + N_EDGES;                       // E
    int* bsum     = qe + N_EDGES;                             // 2*SCAN_B
    int* ebase    = bsum + 2 * SCAN_B;                        // 2*SCAN_B

    // per-launch setup: prop init + type-bucketed CSR build
    init_kernel<<<(N_NODES * DD) / 256, 256, 0, stream>>>(token, emb, prop, cnt,
                                                          se, spi, spo);
    hist_kernel<<<(N_EDGES + 255) / 256, 256, 0, stream>>>(
        etype, src, dst, cnt_in, cnt_out, tcnt, rank_in, rank_out, qe);
    scan1<<<2 * SCAN_B, 1024, 0, stream>>>(cnt_in, cnt_out, in_off, out_off, bsum);
    scan2<<<1, 128, 0, stream>>>(bsum, ebase, in_off, out_off);
    scan3<<<2 * SCAN_B, 1024, 0, stream>>>(in_off, out_off, ebase);
    place_kernel<<<(N_EDGES + 255) / 256, 256, 0, stream>>>(
        src, dst, in_off, out_off, rank_in, rank_out, qe, se, spi, spo);

    // fused cooperative path (grid sized for guaranteed co-residency)
    bool done = false;
    int maxB = 0;
    hipError_t oq =
        hipOccupancyMaxActiveBlocksPerMultiprocessor(&maxB, fused_steps, 256, 0);
    if (oq == hipSuccess && maxB > 0) {
        int grid = maxB * 256;                    // 256 CUs on MI355X
        if (grid > NCHUNK) grid = NCHUNK;
        void* args[] = {
            (void*)&se, (void*)&spi, (void*)&spo, (void*)&W_edge,
            (void*)&W_r, (void*)&b_r, (void*)&W_z, (void*)&b_z,
            (void*)&W_t, (void*)&b_t, (void*)&fea_in, (void*)&fea_out,
            (void*)&in_off, (void*)&out_off, (void*)&prop, (void*)&out};
        hipError_t lr = hipLaunchCooperativeKernel(
            fused_steps, dim3(grid), dim3(256), args, 0, stream);
        if (lr == hipSuccess) done = true;
        else (void)hipGetLastError();             // clear, fall back
    } else {
        (void)hipGetLastError();
    }

    if (!done) {                                  // proven per-step fallback
        for (int step = 0; step < STEPS; ++step) {
            edge_kernel<<<NCHUNK, 256, 0, stream>>>(se, spi, spo, W_edge, prop,
                                                    fea_in, fea_out);
            gru_kernel<<<NGB, 256, 0, stream>>>(
                W_r, b_r, W_z, b_z, W_t, b_t, fea_in, fea_out, in_off, out_off,
                prop, (step == STEPS - 1) ? out : nullptr);
        }
    }
}

// Round 9
// 434.926 us; speedup vs baseline: 2.6259x; 2.6259x over previous
//
#include <hip/hip_runtime.h>

#define N_NODES 50000
#define N_EDGES 100000
#define DD 32
#define STEPS 5
#define ETYPES 8
#define CAP_T 13312              // per-type slot capacity (mult of 64; mean 12500, sigma~105)
#define CAP (ETYPES * CAP_T)     // 106496 sorted slots
#define TRASH N_EDGES            // trash row index in fea arrays (extra row allocated)
#define SCAN_B 49                // 49 blocks * 1024 = 50176 >= N_NODES

#define TPB 32                   // nodes per gru tile
#define NT ((N_NODES + TPB - 1) / TPB)   // 1563 tiles
#define GRU_GRID 768             // 3 blocks/CU (LDS 45.6KB -> 3/CU on 160KB)
#define CAT_STRIDE 68            // floats per cat row: 64 (in|out) + 4 pad -> 17 f4

// prop[n,j] = emb[token[n],j]; zero cnt_in/cnt_out/tcnt; dummy-init sorted slots.
__global__ void init_kernel(const int* __restrict__ token,
                            const float* __restrict__ emb,
                            float* __restrict__ prop,
                            int* __restrict__ cnt,      // 2N+8: cnt_in | cnt_out | tcnt
                            int* __restrict__ se,
                            int* __restrict__ spi,
                            int* __restrict__ spo) {
    int idx = blockIdx.x * 256 + threadIdx.x;   // over N*D = 1.6M, exact grid
    int n = idx >> 5, j = idx & 31;
    prop[idx] = emb[token[n] * DD + j];
    if (idx < 2 * N_NODES + ETYPES) cnt[idx] = 0;
    if (idx < CAP) { se[idx] = 0; spi[idx] = TRASH; spo[idx] = TRASH; }
}

// One pass over edges: per-node ranks (global atomics) + type-bucket slot via
// block-local LDS histogram (one global atomic per type per block for the base).
__global__ void hist_kernel(const int* __restrict__ etype,
                            const int* __restrict__ src,
                            const int* __restrict__ dst,
                            int* __restrict__ cnt_in, int* __restrict__ cnt_out,
                            int* __restrict__ tcnt,
                            int* __restrict__ rank_in, int* __restrict__ rank_out,
                            int* __restrict__ qe) {
    __shared__ int lh[ETYPES], lbase[ETYPES];
    int tid = threadIdx.x;
    int e = blockIdx.x * 256 + tid;
    if (tid < ETYPES) lh[tid] = 0;
    __syncthreads();
    int t = 0, lr = 0;
    bool v = e < N_EDGES;
    if (v) {
        t = etype[e];
        lr = atomicAdd(&lh[t], 1);
        rank_in[e]  = atomicAdd(&cnt_in[dst[e]], 1);
        rank_out[e] = atomicAdd(&cnt_out[src[e]], 1);
    }
    __syncthreads();
    if (tid < ETYPES) lbase[tid] = atomicAdd(&tcnt[tid], lh[tid]);
    __syncthreads();
    if (v) qe[e] = t * CAP_T + lbase[t] + lr;
}

// Hierarchical scan stage 1: block-local exclusive scan (coalesced, wide).
__global__ __launch_bounds__(1024) void
scan1(const int* __restrict__ cnt_in, const int* __restrict__ cnt_out,
      int* __restrict__ off_in, int* __restrict__ off_out,
      int* __restrict__ bsum) {
    __shared__ int s[1024];
    int b = blockIdx.x;
    int ab = (b < SCAN_B) ? b : b - SCAN_B;
    const int* a = (b < SCAN_B) ? cnt_in : cnt_out;
    int* o = (b < SCAN_B) ? off_in : off_out;
    int i = ab * 1024 + threadIdx.x;
    int x = (i < N_NODES) ? a[i] : 0;
    s[threadIdx.x] = x;
    __syncthreads();
    for (int ofs = 1; ofs < 1024; ofs <<= 1) {
        int u = (threadIdx.x >= ofs) ? s[threadIdx.x - ofs] : 0;
        __syncthreads();
        s[threadIdx.x] += u;
        __syncthreads();
    }
    if (i < N_NODES) o[i] = s[threadIdx.x] - x;   // local exclusive
    if (threadIdx.x == 1023) bsum[b] = s[1023];
}

// Stage 2: scan 98 block sums. Since sum(cnt_in)=sum(cnt_out)=E exactly, one
// combined scan with a constant -E correction splits the two arrays.
__global__ void scan2(const int* __restrict__ bsum, int* __restrict__ ebase,
                      int* __restrict__ off_in, int* __restrict__ off_out) {
    __shared__ int s[128];
    int t = threadIdx.x;
    int x = (t < 2 * SCAN_B) ? bsum[t] : 0;
    s[t] = x;
    __syncthreads();
    for (int ofs = 1; ofs < 128; ofs <<= 1) {
        int u = (t >= ofs) ? s[t - ofs] : 0;
        __syncthreads();
        s[t] += u;
        __syncthreads();
    }
    if (t < SCAN_B) ebase[t] = s[t] - x;
    else if (t < 2 * SCAN_B) ebase[t] = s[t] - x - N_EDGES;
    if (t == 0) { off_in[N_NODES] = N_EDGES; off_out[N_NODES] = N_EDGES; }
}

// Stage 3: add scanned block bases.
__global__ __launch_bounds__(1024) void
scan3(int* __restrict__ off_in, int* __restrict__ off_out,
      const int* __restrict__ ebase) {
    int b = blockIdx.x;
    int ab = (b < SCAN_B) ? b : b - SCAN_B;
    int* o = (b < SCAN_B) ? off_in : off_out;
    int i = ab * 1024 + threadIdx.x;
    if (i < N_NODES) o[i] += ebase[b];
}

// Scatter edge records into type-sorted slots with final CSR positions.
__global__ void place_kernel(const int* __restrict__ src,
                             const int* __restrict__ dst,
                             const int* __restrict__ in_off,
                             const int* __restrict__ out_off,
                             const int* __restrict__ rank_in,
                             const int* __restrict__ rank_out,
                             const int* __restrict__ qe,
                             int* __restrict__ se, int* __restrict__ spi,
                             int* __restrict__ spo) {
    int e = blockIdx.x * 256 + threadIdx.x;
    if (e < N_EDGES) {
        int q = qe[e];
        int pi = in_off[dst[e]]  + rank_in[e];
        int po = out_off[src[e]] + rank_out[e];
        if (q < CAP) {                          // guard: never OOB even on 8-sigma
            se[q]  = src[e];
            spi[q] = pi;
            spo[q] = po;
        }
    }
}

// Wave = 16 same-type edges (two half-waves of 8). W column j lives in 64 VGPRs
// per lane for the whole wave: zero weight memory traffic in the inner loop.
// EXACT R7 kernel (proven 413.7 us as part of the full pipeline).
__global__ __launch_bounds__(256) void
edge_kernel(const int* __restrict__ se, const int* __restrict__ spi,
            const int* __restrict__ spo, const float* __restrict__ W_edge,
            const float* __restrict__ prop,
            float* __restrict__ fea_in, float* __restrict__ fea_out) {
    int wid = blockIdx.x * 4 + (threadIdx.x >> 6);
    int lane = threadIdx.x & 63;
    int j = lane & 31;
    int slot0 = wid * 16 + ((lane >> 5) << 3);     // this half-wave's 8 slots
    int type = (wid * 16) / CAP_T;                 // wave-uniform (CAP_T % 16 == 0)
    const float2* Wt = (const float2*)W_edge + (size_t)type * (DD * DD);
    float2 w[DD];
#pragma unroll
    for (int i = 0; i < DD; ++i) w[i] = Wt[i * DD + j];   // 8KB once per wave
    int s[8], pi[8], po[8];
    float h[8];
#pragma unroll
    for (int k = 0; k < 8; ++k) {
        s[k] = se[slot0 + k]; pi[k] = spi[slot0 + k]; po[k] = spo[slot0 + k];
    }
#pragma unroll
    for (int k = 0; k < 8; ++k) h[k] = prop[(size_t)s[k] * DD + j];
    float aF[8] = {0.f,0.f,0.f,0.f,0.f,0.f,0.f,0.f};
    float aR[8] = {0.f,0.f,0.f,0.f,0.f,0.f,0.f,0.f};
#pragma unroll
    for (int i = 0; i < DD; ++i) {
#pragma unroll
        for (int k = 0; k < 8; ++k) {
            float hi = __shfl(h[k], i, 32);        // broadcast within half-wave
            aF[k] = fmaf(hi, w[i].x, aF[k]);
            aR[k] = fmaf(hi, w[i].y, aR[k]);
        }
    }
#pragma unroll
    for (int k = 0; k < 8; ++k) {
        fea_in [(size_t)pi[k] * DD + j] = aF[k];   // plain 128B-row stores
        fea_out[(size_t)po[k] * DD + j] = aR[k];
    }
}

__device__ __forceinline__ void fma4(float (&acc)[4], float c, const float4& w) {
    acc[0] = fmaf(c, w.x, acc[0]);
    acc[1] = fmaf(c, w.y, acc[1]);
    acc[2] = fmaf(c, w.z, acc[2]);
    acc[3] = fmaf(c, w.w, acc[3]);
}
__device__ __forceinline__ float sigm(float x) {
    return 1.f / (1.f + __expf(-x));
}
__device__ __forceinline__ float fast_tanh(float x) {
    x = fminf(fmaxf(x, -15.f), 15.f);
    float e = __expf(2.f * x);
    return (e - 1.f) / (e + 1.f);
}

// Persistent GRU: 768 blocks (3/CU via 45.6KB LDS), weights staged to LDS ONCE
// per block, then each block walks a CONTIGUOUS range of 32-node tiles (fea
// reads stay streaming/L2-local). High occupancy (12 waves/CU) + LDS weights
// is the combination R6 (high occ, global W = 87us) and R7 (low occ, LDS W =
// 42us) each had half of. Per tile: one (node,c4) gather pair per thread ->
// cat; matvec rows 0-63 from cat, rows 64-95 via 8-lane shfl of reg-prop.
__global__ __launch_bounds__(256) void
gru_kernel(const float* __restrict__ W_r, const float* __restrict__ b_r,
           const float* __restrict__ W_z, const float* __restrict__ b_z,
           const float* __restrict__ W_t, const float* __restrict__ b_t,
           const float* __restrict__ fea_in,
           const float* __restrict__ fea_out,
           const int* __restrict__ in_off,
           const int* __restrict__ out_off,
           float* __restrict__ prop,
           float* __restrict__ out2) {
    __shared__ float4 wlds[3 * 96 * 8];               // 36.9 KB: W_r|W_z|W_t
    __shared__ float cat[TPB * CAT_STRIDE];           // 8.7 KB
    float4* cat4 = (float4*)cat;                      // row stride 17 float4
    const int tid = threadIdx.x;
    const int jq = tid & 7;
    const int ng = tid >> 3;                          // node-in-tile 0..31

    // ---- stage weights -> LDS once per block ----
    {
        const float4* wr4 = (const float4*)W_r;       // 768 float4 each
        const float4* wz4 = (const float4*)W_z;
        const float4* wt4 = (const float4*)W_t;
#pragma unroll
        for (int q = 0; q < 3; ++q) {
            int i = q * 256 + tid;
            wlds[i]        = wr4[i];
            wlds[768 + i]  = wz4[i];
            wlds[1536 + i] = wt4[i];
        }
    }
    float4 br = ((const float4*)b_r)[jq];
    float4 bz = ((const float4*)b_z)[jq];
    float4 bt = ((const float4*)b_t)[jq];

    // contiguous tile range for this block
    const int G = gridDim.x;
    int t0 = (int)(((long long)blockIdx.x * NT) / G);
    int t1 = (int)(((long long)(blockIdx.x + 1) * NT) / G);

    for (int t = t0; t < t1; ++t) {
        const int n0 = t * TPB;
        const int gn = n0 + ng;
        __syncthreads();                              // cat free (prev readers done)

        // prop -> registers; gather one (node,c4) pair into cat
        float p_[4];
        {
            const float4 zz = {0.f, 0.f, 0.f, 0.f};
            float4 p = (gn < N_NODES)
                           ? ((const float4*)(prop + (size_t)n0 * DD))[tid] : zz;
            p_[0] = p.x; p_[1] = p.y; p_[2] = p.z; p_[3] = p.w;

            const float4* fi4 = (const float4*)fea_in;    // row = 8 float4
            const float4* fo4 = (const float4*)fea_out;
            float4 va = zz, vb = zz;
            if (gn < N_NODES) {
                int i0 = in_off[gn], i1 = in_off[gn + 1];
                for (int r = i0; r < i1; ++r) {
                    float4 x = fi4[(size_t)r * 8 + jq];
                    va.x += x.x; va.y += x.y; va.z += x.z; va.w += x.w;
                }
                int o0 = out_off[gn], o1 = out_off[gn + 1];
                for (int r = o0; r < o1; ++r) {
                    float4 x = fo4[(size_t)r * 8 + jq];
                    vb.x += x.x; vb.y += x.y; vb.z += x.z; vb.w += x.w;
                }
            }
            cat4[ng * 17 + jq]     = va;
            cat4[ng * 17 + 8 + jq] = vb;
        }
        __syncthreads();

        // phase A: r,z
        float r_[4] = {br.x, br.y, br.z, br.w};
        float z_[4] = {bz.x, bz.y, bz.z, bz.w};
#pragma unroll 1
        for (int g = 0; g < 16; ++g) {                // rows 0..63 from cat
            int m0 = g * 4;
            float4 wr[4], wz[4];
#pragma unroll
            for (int i = 0; i < 4; ++i) {
                wr[i] = wlds[(m0 + i) * 8 + jq];
                wz[i] = wlds[768 + (m0 + i) * 8 + jq];
            }
            float4 c = cat4[ng * 17 + g];
            fma4(r_, c.x, wr[0]); fma4(r_, c.y, wr[1]);
            fma4(r_, c.z, wr[2]); fma4(r_, c.w, wr[3]);
            fma4(z_, c.x, wz[0]); fma4(z_, c.y, wz[1]);
            fma4(z_, c.z, wz[2]); fma4(z_, c.w, wz[3]);
        }
#pragma unroll 1
        for (int i2 = 0; i2 < 8; ++i2) {              // rows 64..95: prop shfl
            float4 wr[4], wz[4];
#pragma unroll
            for (int c = 0; c < 4; ++c) {
                wr[c] = wlds[(64 + i2 * 4 + c) * 8 + jq];
                wz[c] = wlds[768 + (64 + i2 * 4 + c) * 8 + jq];
            }
            float pc0 = __shfl(p_[0], i2, 8);
            float pc1 = __shfl(p_[1], i2, 8);
            float pc2 = __shfl(p_[2], i2, 8);
            float pc3 = __shfl(p_[3], i2, 8);
            fma4(r_, pc0, wr[0]); fma4(r_, pc1, wr[1]);
            fma4(r_, pc2, wr[2]); fma4(r_, pc3, wr[3]);
            fma4(z_, pc0, wz[0]); fma4(z_, pc1, wz[1]);
            fma4(z_, pc2, wz[2]); fma4(z_, pc3, wz[3]);
        }
#pragma unroll
        for (int j = 0; j < 4; ++j) {
            r_[j] = sigm(r_[j]) * p_[j];              // r := r*p
            z_[j] = sigm(z_[j]);
        }

        // phase B: t
        float t_[4] = {bt.x, bt.y, bt.z, bt.w};
#pragma unroll 1
        for (int g = 0; g < 16; ++g) {
            int m0 = g * 4;
            float4 wt[4];
#pragma unroll
            for (int i = 0; i < 4; ++i)
                wt[i] = wlds[1536 + (m0 + i) * 8 + jq];
            float4 c = cat4[ng * 17 + g];
            fma4(t_, c.x, wt[0]); fma4(t_, c.y, wt[1]);
            fma4(t_, c.z, wt[2]); fma4(t_, c.w, wt[3]);
        }
#pragma unroll 1
        for (int i2 = 0; i2 < 8; ++i2) {
            float4 wt[4];
#pragma unroll
            for (int c = 0; c < 4; ++c)
                wt[c] = wlds[1536 + (64 + i2 * 4 + c) * 8 + jq];
            float rc0 = __shfl(r_[0], i2, 8);
            float rc1 = __shfl(r_[1], i2, 8);
            float rc2 = __shfl(r_[2], i2, 8);
            float rc3 = __shfl(r_[3], i2, 8);
            fma4(t_, rc0, wt[0]); fma4(t_, rc1, wt[1]);
            fma4(t_, rc2, wt[2]); fma4(t_, rc3, wt[3]);
        }

        // update: prop = p + z*(tanh(t) - p); final step also writes out2
        if (gn < N_NODES) {
            float4 o;
            o.x = fmaf(z_[0], fast_tanh(t_[0]) - p_[0], p_[0]);
            o.y = fmaf(z_[1], fast_tanh(t_[1]) - p_[1], p_[1]);
            o.z = fmaf(z_[2], fast_tanh(t_[2]) - p_[2], p_[2]);
            o.w = fmaf(z_[3], fast_tanh(t_[3]) - p_[3], p_[3]);
            ((float4*)(prop + (size_t)gn * DD))[jq] = o;
            if (out2) ((float4*)(out2 + (size_t)gn * DD))[jq] = o;
        }
    }
}

extern "C" void kernel_launch(void* const* d_in, const int* in_sizes, int n_in,
                              void* d_out, int out_size, void* d_ws, size_t ws_size,
                              hipStream_t stream) {
    const int*   token  = (const int*)d_in[0];
    const int*   etype  = (const int*)d_in[1];
    const int*   src    = (const int*)d_in[2];
    const int*   dst    = (const int*)d_in[3];
    const float* emb    = (const float*)d_in[4];
    const float* W_edge = (const float*)d_in[5];
    const float* W_r    = (const float*)d_in[6];
    const float* b_r    = (const float*)d_in[7];
    const float* W_z    = (const float*)d_in[8];
    const float* b_z    = (const float*)d_in[9];
    const float* W_t    = (const float*)d_in[10];
    const float* b_t    = (const float*)d_in[11];
    float* out = (float*)d_out;

    // Persistent workspace (~33 MB; ws_size = 256 MB per the poison fill):
    float* prop    = (float*)d_ws;                            // N*D
    float* fea_in  = prop    + (size_t)N_NODES * DD;          // (E+1)*D
    float* fea_out = fea_in  + (size_t)(N_EDGES + 1) * DD;    // (E+1)*D
    int* in_off   = (int*)(fea_out + (size_t)(N_EDGES + 1) * DD); // N+1
    int* out_off  = in_off + (N_NODES + 1);                   // N+1
    int* se       = out_off + (N_NODES + 1);                  // CAP
    int* spi      = se + CAP;                                 // CAP
    int* spo      = spi + CAP;                                // CAP

    // Setup temporaries OVERLAID on fea_in (dead before first edge write).
    int* cnt      = (int*)fea_in;                             // 2N+8
    int* cnt_in   = cnt;
    int* cnt_out  = cnt + N_NODES;
    int* tcnt     = cnt + 2 * N_NODES;
    int* rank_in  = cnt + 2 * N_NODES + ETYPES;               // E
    int* rank_out = rank_in + N_EDGES;                        // E
    int* qe       = rank_out + N_EDGES;                       // E
    int* bsum     = qe + N_EDGES;                             // 2*SCAN_B
    int* ebase    = bsum + 2 * SCAN_B;                        // 2*SCAN_B

    // per-launch setup: prop init + type-bucketed CSR build
    init_kernel<<<(N_NODES * DD) / 256, 256, 0, stream>>>(token, emb, prop, cnt,
                                                          se, spi, spo);
    hist_kernel<<<(N_EDGES + 255) / 256, 256, 0, stream>>>(
        etype, src, dst, cnt_in, cnt_out, tcnt, rank_in, rank_out, qe);
    scan1<<<2 * SCAN_B, 1024, 0, stream>>>(cnt_in, cnt_out, in_off, out_off, bsum);
    scan2<<<1, 128, 0, stream>>>(bsum, ebase, in_off, out_off);
    scan3<<<2 * SCAN_B, 1024, 0, stream>>>(in_off, out_off, ebase);
    place_kernel<<<(N_EDGES + 255) / 256, 256, 0, stream>>>(
        src, dst, in_off, out_off, rank_in, rank_out, qe, se, spi, spo);

    for (int step = 0; step < STEPS; ++step) {
        edge_kernel<<<CAP / 64, 256, 0, stream>>>(se, spi, spo, W_edge, prop,
                                                  fea_in, fea_out);
        gru_kernel<<<GRU_GRID, 256, 0, stream>>>(
            W_r, b_r, W_z, b_z, W_t, b_t, fea_in, fea_out, in_off, out_off,
            prop, (step == STEPS - 1) ? out : nullptr);
    }
}

// Round 10
// 414.179 us; speedup vs baseline: 2.7575x; 1.0501x over previous
//
#include <hip/hip_runtime.h>

#define N_NODES 50000
#define N_EDGES 100000
#define DD 32
#define STEPS 5
#define ETYPES 8
#define CAP_T 13312              // per-type slot capacity (mult of 64; mean 12500, sigma~105)
#define CAP (ETYPES * CAP_T)     // 106496 sorted slots
#define TRASH N_EDGES            // trash row index in fea arrays (extra row allocated)
#define SCAN_B 49                // 49 blocks * 1024 = 50176 >= N_NODES

#define NG8 (N_NODES / 8)        // 6250 8-node wave groups (exact: 50000 = 6250*8)
#define GRU_GRID ((NG8 + 3) / 4) // 1563 blocks of 4 waves, 1 group/wave

// prop[n,j] = emb[token[n],j]; zero cnt_in/cnt_out/tcnt; dummy-init sorted slots.
__global__ void init_kernel(const int* __restrict__ token,
                            const float* __restrict__ emb,
                            float* __restrict__ prop,
                            int* __restrict__ cnt,      // 2N+8: cnt_in | cnt_out | tcnt
                            int* __restrict__ se,
                            int* __restrict__ spi,
                            int* __restrict__ spo) {
    int idx = blockIdx.x * 256 + threadIdx.x;   // over N*D = 1.6M, exact grid
    int n = idx >> 5, j = idx & 31;
    prop[idx] = emb[token[n] * DD + j];
    if (idx < 2 * N_NODES + ETYPES) cnt[idx] = 0;
    if (idx < CAP) { se[idx] = 0; spi[idx] = TRASH; spo[idx] = TRASH; }
}

// One pass over edges: per-node ranks (global atomics) + type-bucket slot via
// block-local LDS histogram (one global atomic per type per block for the base).
__global__ void hist_kernel(const int* __restrict__ etype,
                            const int* __restrict__ src,
                            const int* __restrict__ dst,
                            int* __restrict__ cnt_in, int* __restrict__ cnt_out,
                            int* __restrict__ tcnt,
                            int* __restrict__ rank_in, int* __restrict__ rank_out,
                            int* __restrict__ qe) {
    __shared__ int lh[ETYPES], lbase[ETYPES];
    int tid = threadIdx.x;
    int e = blockIdx.x * 256 + tid;
    if (tid < ETYPES) lh[tid] = 0;
    __syncthreads();
    int t = 0, lr = 0;
    bool v = e < N_EDGES;
    if (v) {
        t = etype[e];
        lr = atomicAdd(&lh[t], 1);
        rank_in[e]  = atomicAdd(&cnt_in[dst[e]], 1);
        rank_out[e] = atomicAdd(&cnt_out[src[e]], 1);
    }
    __syncthreads();
    if (tid < ETYPES) lbase[tid] = atomicAdd(&tcnt[tid], lh[tid]);
    __syncthreads();
    if (v) qe[e] = t * CAP_T + lbase[t] + lr;
}

// Hierarchical scan stage 1: block-local exclusive scan (coalesced, wide).
__global__ __launch_bounds__(1024) void
scan1(const int* __restrict__ cnt_in, const int* __restrict__ cnt_out,
      int* __restrict__ off_in, int* __restrict__ off_out,
      int* __restrict__ bsum) {
    __shared__ int s[1024];
    int b = blockIdx.x;
    int ab = (b < SCAN_B) ? b : b - SCAN_B;
    const int* a = (b < SCAN_B) ? cnt_in : cnt_out;
    int* o = (b < SCAN_B) ? off_in : off_out;
    int i = ab * 1024 + threadIdx.x;
    int x = (i < N_NODES) ? a[i] : 0;
    s[threadIdx.x] = x;
    __syncthreads();
    for (int ofs = 1; ofs < 1024; ofs <<= 1) {
        int u = (threadIdx.x >= ofs) ? s[threadIdx.x - ofs] : 0;
        __syncthreads();
        s[threadIdx.x] += u;
        __syncthreads();
    }
    if (i < N_NODES) o[i] = s[threadIdx.x] - x;   // local exclusive
    if (threadIdx.x == 1023) bsum[b] = s[1023];
}

// Stage 2: scan 98 block sums. Since sum(cnt_in)=sum(cnt_out)=E exactly, one
// combined scan with a constant -E correction splits the two arrays.
__global__ void scan2(const int* __restrict__ bsum, int* __restrict__ ebase,
                      int* __restrict__ off_in, int* __restrict__ off_out) {
    __shared__ int s[128];
    int t = threadIdx.x;
    int x = (t < 2 * SCAN_B) ? bsum[t] : 0;
    s[t] = x;
    __syncthreads();
    for (int ofs = 1; ofs < 128; ofs <<= 1) {
        int u = (t >= ofs) ? s[t - ofs] : 0;
        __syncthreads();
        s[t] += u;
        __syncthreads();
    }
    if (t < SCAN_B) ebase[t] = s[t] - x;
    else if (t < 2 * SCAN_B) ebase[t] = s[t] - x - N_EDGES;
    if (t == 0) { off_in[N_NODES] = N_EDGES; off_out[N_NODES] = N_EDGES; }
}

// Stage 3: add scanned block bases.
__global__ __launch_bounds__(1024) void
scan3(int* __restrict__ off_in, int* __restrict__ off_out,
      const int* __restrict__ ebase) {
    int b = blockIdx.x;
    int ab = (b < SCAN_B) ? b : b - SCAN_B;
    int* o = (b < SCAN_B) ? off_in : off_out;
    int i = ab * 1024 + threadIdx.x;
    if (i < N_NODES) o[i] += ebase[b];
}

// Scatter edge records into type-sorted slots with final CSR positions.
__global__ void place_kernel(const int* __restrict__ src,
                             const int* __restrict__ dst,
                             const int* __restrict__ in_off,
                             const int* __restrict__ out_off,
                             const int* __restrict__ rank_in,
                             const int* __restrict__ rank_out,
                             const int* __restrict__ qe,
                             int* __restrict__ se, int* __restrict__ spi,
                             int* __restrict__ spo) {
    int e = blockIdx.x * 256 + threadIdx.x;
    if (e < N_EDGES) {
        int q = qe[e];
        int pi = in_off[dst[e]]  + rank_in[e];
        int po = out_off[src[e]] + rank_out[e];
        if (q < CAP) {                          // guard: never OOB even on 8-sigma
            se[q]  = src[e];
            spi[q] = pi;
            spo[q] = po;
        }
    }
}

// Wave = 16 same-type edges (two half-waves of 8). W column j lives in 64 VGPRs
// per lane for the whole wave: zero weight memory traffic in the inner loop.
// EXACT R7/R9 kernel (proven in the 413.7us pipeline).
__global__ __launch_bounds__(256) void
edge_kernel(const int* __restrict__ se, const int* __restrict__ spi,
            const int* __restrict__ spo, const float* __restrict__ W_edge,
            const float* __restrict__ prop,
            float* __restrict__ fea_in, float* __restrict__ fea_out) {
    int wid = blockIdx.x * 4 + (threadIdx.x >> 6);
    int lane = threadIdx.x & 63;
    int j = lane & 31;
    int slot0 = wid * 16 + ((lane >> 5) << 3);     // this half-wave's 8 slots
    int type = (wid * 16) / CAP_T;                 // wave-uniform (CAP_T % 16 == 0)
    const float2* Wt = (const float2*)W_edge + (size_t)type * (DD * DD);
    float2 w[DD];
#pragma unroll
    for (int i = 0; i < DD; ++i) w[i] = Wt[i * DD + j];   // 8KB once per wave
    int s[8], pi[8], po[8];
    float h[8];
#pragma unroll
    for (int k = 0; k < 8; ++k) {
        s[k] = se[slot0 + k]; pi[k] = spi[slot0 + k]; po[k] = spo[slot0 + k];
    }
#pragma unroll
    for (int k = 0; k < 8; ++k) h[k] = prop[(size_t)s[k] * DD + j];
    float aF[8] = {0.f,0.f,0.f,0.f,0.f,0.f,0.f,0.f};
    float aR[8] = {0.f,0.f,0.f,0.f,0.f,0.f,0.f,0.f};
#pragma unroll
    for (int i = 0; i < DD; ++i) {
#pragma unroll
        for (int k = 0; k < 8; ++k) {
            float hi = __shfl(h[k], i, 32);        // broadcast within half-wave
            aF[k] = fmaf(hi, w[i].x, aF[k]);
            aR[k] = fmaf(hi, w[i].y, aR[k]);
        }
    }
#pragma unroll
    for (int k = 0; k < 8; ++k) {
        fea_in [(size_t)pi[k] * DD + j] = aF[k];   // plain 128B-row stores
        fea_out[(size_t)po[k] * DD + j] = aR[k];
    }
}

__device__ __forceinline__ void fma4(float (&acc)[4], float c, const float4& w) {
    acc[0] = fmaf(c, w.x, acc[0]);
    acc[1] = fmaf(c, w.y, acc[1]);
    acc[2] = fmaf(c, w.z, acc[2]);
    acc[3] = fmaf(c, w.w, acc[3]);
}
__device__ __forceinline__ float sigm(float x) {
    return 1.f / (1.f + __expf(-x));
}
__device__ __forceinline__ float fast_tanh(float x) {
    x = fminf(fmaxf(x, -15.f), 15.f);
    float e = __expf(2.f * x);
    return (e - 1.f) / (e + 1.f);
}

// Cat-free GRU. One wave = 8 nodes (lane = node*8 + jq); gather produces the
// node's in/out slices (va,vb) directly in registers; the matvec broadcasts
// them across the node's 8 lanes with __shfl(.,g,8) — same pattern as prop
// (proven R5-R9). LDS holds ONLY the weights (36.9 KB -> 4 blocks/CU,
// 16 waves/CU) and there are ZERO barriers after the weight staging: waves
// slip freely against each other's gather latency.
__global__ __launch_bounds__(256, 4) void
gru_kernel(const float* __restrict__ W_r, const float* __restrict__ b_r,
           const float* __restrict__ W_z, const float* __restrict__ b_z,
           const float* __restrict__ W_t, const float* __restrict__ b_t,
           const float* __restrict__ fea_in,
           const float* __restrict__ fea_out,
           const int* __restrict__ in_off,
           const int* __restrict__ out_off,
           float* __restrict__ prop,
           float* __restrict__ out2) {
    __shared__ float4 wlds[3 * 96 * 8];               // 36864 B: W_r|W_z|W_t
    const int tid = threadIdx.x;
    // ---- stage weights -> LDS once per block ----
    {
        const float4* wr4 = (const float4*)W_r;       // 768 float4 each
        const float4* wz4 = (const float4*)W_z;
        const float4* wt4 = (const float4*)W_t;
#pragma unroll
        for (int q = 0; q < 3; ++q) {
            int i = q * 256 + tid;
            wlds[i]        = wr4[i];
            wlds[768 + i]  = wz4[i];
            wlds[1536 + i] = wt4[i];
        }
    }
    __syncthreads();                                  // the ONLY barrier

    const int wv = blockIdx.x * 4 + (tid >> 6);       // wave id = 8-node group
    if (wv >= NG8) return;
    const int lane = tid & 63;
    const int jq = lane & 7;
    const int gn = wv * 8 + (lane >> 3);              // this thread's node

    // ---- gather: prop slice + in/out segment-sum slices -> registers ----
    float p_[4], va[4], vb[4];
    {
        float4 p = ((const float4*)prop)[(size_t)gn * 8 + jq];
        p_[0] = p.x; p_[1] = p.y; p_[2] = p.z; p_[3] = p.w;
        va[0] = va[1] = va[2] = va[3] = 0.f;
        vb[0] = vb[1] = vb[2] = vb[3] = 0.f;
        const float4* fi4 = (const float4*)fea_in;    // row = 8 float4
        const float4* fo4 = (const float4*)fea_out;
        int i0 = in_off[gn], i1 = in_off[gn + 1];
        for (int r = i0; r < i1; ++r) {
            float4 x = fi4[(size_t)r * 8 + jq];
            va[0] += x.x; va[1] += x.y; va[2] += x.z; va[3] += x.w;
        }
        int o0 = out_off[gn], o1 = out_off[gn + 1];
        for (int r = o0; r < o1; ++r) {
            float4 x = fo4[(size_t)r * 8 + jq];
            vb[0] += x.x; vb[1] += x.y; vb[2] += x.z; vb[3] += x.w;
        }
    }

    // ---- phase A: r,z ----
    float4 br = ((const float4*)b_r)[jq];
    float4 bz = ((const float4*)b_z)[jq];
    float r_[4] = {br.x, br.y, br.z, br.w};
    float z_[4] = {bz.x, bz.y, bz.z, bz.w};
#pragma unroll 1
    for (int g = 0; g < 8; ++g) {                     // rows 0..31: in via shfl
        float4 wr[4], wz[4];
#pragma unroll
        for (int i = 0; i < 4; ++i) {
            wr[i] = wlds[(g * 4 + i) * 8 + jq];
            wz[i] = wlds[768 + (g * 4 + i) * 8 + jq];
        }
        float c0 = __shfl(va[0], g, 8);
        float c1 = __shfl(va[1], g, 8);
        float c2 = __shfl(va[2], g, 8);
        float c3 = __shfl(va[3], g, 8);
        fma4(r_, c0, wr[0]); fma4(r_, c1, wr[1]);
        fma4(r_, c2, wr[2]); fma4(r_, c3, wr[3]);
        fma4(z_, c0, wz[0]); fma4(z_, c1, wz[1]);
        fma4(z_, c2, wz[2]); fma4(z_, c3, wz[3]);
    }
#pragma unroll 1
    for (int g = 0; g < 8; ++g) {                     // rows 32..63: out via shfl
        float4 wr[4], wz[4];
#pragma unroll
        for (int i = 0; i < 4; ++i) {
            wr[i] = wlds[(32 + g * 4 + i) * 8 + jq];
            wz[i] = wlds[768 + (32 + g * 4 + i) * 8 + jq];
        }
        float c0 = __shfl(vb[0], g, 8);
        float c1 = __shfl(vb[1], g, 8);
        float c2 = __shfl(vb[2], g, 8);
        float c3 = __shfl(vb[3], g, 8);
        fma4(r_, c0, wr[0]); fma4(r_, c1, wr[1]);
        fma4(r_, c2, wr[2]); fma4(r_, c3, wr[3]);
        fma4(z_, c0, wz[0]); fma4(z_, c1, wz[1]);
        fma4(z_, c2, wz[2]); fma4(z_, c3, wz[3]);
    }
#pragma unroll 1
    for (int i2 = 0; i2 < 8; ++i2) {                  // rows 64..95: prop via shfl
        float4 wr[4], wz[4];
#pragma unroll
        for (int c = 0; c < 4; ++c) {
            wr[c] = wlds[(64 + i2 * 4 + c) * 8 + jq];
            wz[c] = wlds[768 + (64 + i2 * 4 + c) * 8 + jq];
        }
        float pc0 = __shfl(p_[0], i2, 8);
        float pc1 = __shfl(p_[1], i2, 8);
        float pc2 = __shfl(p_[2], i2, 8);
        float pc3 = __shfl(p_[3], i2, 8);
        fma4(r_, pc0, wr[0]); fma4(r_, pc1, wr[1]);
        fma4(r_, pc2, wr[2]); fma4(r_, pc3, wr[3]);
        fma4(z_, pc0, wz[0]); fma4(z_, pc1, wz[1]);
        fma4(z_, pc2, wz[2]); fma4(z_, pc3, wz[3]);
    }
#pragma unroll
    for (int j = 0; j < 4; ++j) {
        r_[j] = sigm(r_[j]) * p_[j];                  // r := r*p
        z_[j] = sigm(z_[j]);
    }

    // ---- phase B: t ----
    float4 bt = ((const float4*)b_t)[jq];
    float t_[4] = {bt.x, bt.y, bt.z, bt.w};
#pragma unroll 1
    for (int g = 0; g < 8; ++g) {                     // rows 0..31: in
        float4 wt[4];
#pragma unroll
        for (int i = 0; i < 4; ++i)
            wt[i] = wlds[1536 + (g * 4 + i) * 8 + jq];
        float c0 = __shfl(va[0], g, 8);
        float c1 = __shfl(va[1], g, 8);
        float c2 = __shfl(va[2], g, 8);
        float c3 = __shfl(va[3], g, 8);
        fma4(t_, c0, wt[0]); fma4(t_, c1, wt[1]);
        fma4(t_, c2, wt[2]); fma4(t_, c3, wt[3]);
    }
#pragma unroll 1
    for (int g = 0; g < 8; ++g) {                     // rows 32..63: out
        float4 wt[4];
#pragma unroll
        for (int i = 0; i < 4; ++i)
            wt[i] = wlds[1536 + (32 + g * 4 + i) * 8 + jq];
        float c0 = __shfl(vb[0], g, 8);
        float c1 = __shfl(vb[1], g, 8);
        float c2 = __shfl(vb[2], g, 8);
        float c3 = __shfl(vb[3], g, 8);
        fma4(t_, c0, wt[0]); fma4(t_, c1, wt[1]);
        fma4(t_, c2, wt[2]); fma4(t_, c3, wt[3]);
    }
#pragma unroll 1
    for (int i2 = 0; i2 < 8; ++i2) {                  // rows 64..95: r*p
        float4 wt[4];
#pragma unroll
        for (int c = 0; c < 4; ++c)
            wt[c] = wlds[1536 + (64 + i2 * 4 + c) * 8 + jq];
        float rc0 = __shfl(r_[0], i2, 8);
        float rc1 = __shfl(r_[1], i2, 8);
        float rc2 = __shfl(r_[2], i2, 8);
        float rc3 = __shfl(r_[3], i2, 8);
        fma4(t_, rc0, wt[0]); fma4(t_, rc1, wt[1]);
        fma4(t_, rc2, wt[2]); fma4(t_, rc3, wt[3]);
    }

    // ---- update: prop = p + z*(tanh(t) - p); final step also writes out2 ----
    float4 o;
    o.x = fmaf(z_[0], fast_tanh(t_[0]) - p_[0], p_[0]);
    o.y = fmaf(z_[1], fast_tanh(t_[1]) - p_[1], p_[1]);
    o.z = fmaf(z_[2], fast_tanh(t_[2]) - p_[2], p_[2]);
    o.w = fmaf(z_[3], fast_tanh(t_[3]) - p_[3], p_[3]);
    ((float4*)prop)[(size_t)gn * 8 + jq] = o;
    if (out2) ((float4*)out2)[(size_t)gn * 8 + jq] = o;
}

extern "C" void kernel_launch(void* const* d_in, const int* in_sizes, int n_in,
                              void* d_out, int out_size, void* d_ws, size_t ws_size,
                              hipStream_t stream) {
    const int*   token  = (const int*)d_in[0];
    const int*   etype  = (const int*)d_in[1];
    const int*   src    = (const int*)d_in[2];
    const int*   dst    = (const int*)d_in[3];
    const float* emb    = (const float*)d_in[4];
    const float* W_edge = (const float*)d_in[5];
    const float* W_r    = (const float*)d_in[6];
    const float* b_r    = (const float*)d_in[7];
    const float* W_z    = (const float*)d_in[8];
    const float* b_z    = (const float*)d_in[9];
    const float* W_t    = (const float*)d_in[10];
    const float* b_t    = (const float*)d_in[11];
    float* out = (float*)d_out;

    // Persistent workspace (~33 MB; ws_size = 256 MB per the poison fill):
    float* prop    = (float*)d_ws;                            // N*D
    float* fea_in  = prop    + (size_t)N_NODES * DD;          // (E+1)*D
    float* fea_out = fea_in  + (size_t)(N_EDGES + 1) * DD;    // (E+1)*D
    int* in_off   = (int*)(fea_out + (size_t)(N_EDGES + 1) * DD); // N+1
    int* out_off  = in_off + (N_NODES + 1);                   // N+1
    int* se       = out_off + (N_NODES + 1);                  // CAP
    int* spi      = se + CAP;                                 // CAP
    int* spo      = spi + CAP;                                // CAP

    // Setup temporaries OVERLAID on fea_in (dead before first edge write).
    int* cnt      = (int*)fea_in;                             // 2N+8
    int* cnt_in   = cnt;
    int* cnt_out  = cnt + N_NODES;
    int* tcnt     = cnt + 2 * N_NODES;
    int* rank_in  = cnt + 2 * N_NODES + ETYPES;               // E
    int* rank_out = rank_in + N_EDGES;                        // E
    int* qe       = rank_out + N_EDGES;                       // E
    int* bsum     = qe + N_EDGES;                             // 2*SCAN_B
    int* ebase    = bsum + 2 * SCAN_B;                        // 2*SCAN_B

    // per-launch setup: prop init + type-bucketed CSR build
    init_kernel<<<(N_NODES * DD) / 256, 256, 0, stream>>>(token, emb, prop, cnt,
                                                          se, spi, spo);
    hist_kernel<<<(N_EDGES + 255) / 256, 256, 0, stream>>>(
        etype, src, dst, cnt_in, cnt_out, tcnt, rank_in, rank_out, qe);
    scan1<<<2 * SCAN_B, 1024, 0, stream>>>(cnt_in, cnt_out, in_off, out_off, bsum);
    scan2<<<1, 128, 0, stream>>>(bsum, ebase, in_off, out_off);
    scan3<<<2 * SCAN_B, 1024, 0, stream>>>(in_off, out_off, ebase);
    place_kernel<<<(N_EDGES + 255) / 256, 256, 0, stream>>>(
        src, dst, in_off, out_off, rank_in, rank_out, qe, se, spi, spo);

    for (int step = 0; step < STEPS; ++step) {
        edge_kernel<<<CAP / 64, 256, 0, stream>>>(se, spi, spo, W_edge, prop,
                                                  fea_in, fea_out);
        gru_kernel<<<GRU_GRID, 256, 0, stream>>>(
            W_r, b_r, W_z, b_z, W_t, b_t, fea_in, fea_out, in_off, out_off,
            prop, (step == STEPS - 1) ? out : nullptr);
    }
}